// Round 12
// baseline (109.761 us; speedup 1.0000x reference)
//
#include <hip/hip_runtime.h>
#include <hip/hip_bf16.h>

#define HWPX 589824          // 768*768
#define MPIX 2359296         // 4*768*768
#define EPSF 1e-7f
#define LN2F 0.6931471805599453f
#define TILE 1024            // px per tile
#define NT   9               // tiles per block
#define BLKPX 9216           // 64 blocks/image exactly -> never straddles
#define NBLK 256             // one block per CU

// ws float layout:
// [0..2]   cls: bce_log2sum, inter, sum_p
// [3..5]   pred ch0 vs (1-tfg): bce_log2sum, inter, sum_p
// [6..21]  a_sum[k]  = sum log2(1-pc), channels k=0..15 (pred ch 1..16)
// [22..37] sum_p[k]
// [38..293]  segD[n*16+k]   (log2 units)
// [294..549] segP[n*16+k]
// [550..565] cntf[n]  float counts of ids 1..16

typedef __attribute__((ext_vector_type(8))) short bf16x8;
typedef __attribute__((ext_vector_type(4))) float f32x4;

__device__ __forceinline__ short bfc(float x) {
    union { __hip_bfloat16 h; short s; } u;
    u.h = __float2bfloat16(x);
    return u.s;
}

__device__ __forceinline__ float wave_sum64(float v) {
#pragma unroll
    for (int o = 32; o; o >>= 1) v += __shfl_xor(v, o, 64);
    return v;
}

// opaque loads: emitted in place, kept live to consumption (R11-verified)
#define ALOADF4(dst, addr) \
    asm volatile("global_load_dwordx4 %0, %1, off" : "=&v"(dst) : "v"(addr) : "memory")
#define ALOADI4(dst, addr) \
    asm volatile("global_load_dwordx4 %0, %1, off" : "=&v"(dst) : "v"(addr) : "memory")
#define VMDRAIN do { \
    asm volatile("s_waitcnt vmcnt(0)" ::: "memory"); \
    __builtin_amdgcn_sched_barrier(0); } while (0)

__global__ __launch_bounds__(512) void loss_main(
    const float* __restrict__ pred, const float* __restrict__ cls,
    const int* __restrict__ tm, float* __restrict__ acc)
{
    // bf16 D/P tiles: row padded to 1032 el (2064 B -> q-stride = 4 banks, ~2-way)
    __shared__ __attribute__((aligned(16))) short Dst[2][16][1032];  // 66 KB
    __shared__ __attribute__((aligned(16))) short Pst[2][16][1032];  // 66 KB
    __shared__ __attribute__((aligned(16))) int   tmt[2][1024];      // 8 KB
    __shared__ float gD[256], gP[256];                               // 2 KB
    __shared__ float sCnt[16][8];
    __shared__ float sC6[6][8];

    const int tid  = threadIdx.x;
    const int w    = tid >> 6;       // wave 0..7
    const int lane = tid & 63;
    const int g    = lane >> 4;      // px subgroup 0..3
    const int q    = lane & 15;      // bin/channel index in MFMA

    // XCD swizzle: same-XCD blocks take ADJACENT px regions (dense per-XCD streams)
    const int r   = ((blockIdx.x & 7) << 5) + (blockIdx.x >> 3);
    const int b   = r >> 6;                 // image
    const int off = (r & 63) * BLKPX;       // px offset in image

    const int*   trow    = tm + (long)b * HWPX + off;
    const float* pbase17 = pred + (long)b * 17 * (long)HWPX + off;
    const int k0 = w, k1 = w + 8;           // this wave's channels (0-based)
    const float* prow0 = pbase17 + (long)(1 + k0) * HWPX;
    const float* prow1 = pbase17 + (long)(1 + k1) * HWPX;

    if (tid < 256) { gD[tid] = 0.f; gP[tid] = 0.f; }

    float4 L[8];  int4 T[4];
    // stage-issue: per plane, lane owns px [h*512 + lane*8, +8) for h=0,1 (contig 4KB bursts)
#define ISSUE(ts) do { const int t0 = (ts) * TILE;                         \
        ALOADF4(L[0], prow0 + t0 + lane * 8);                              \
        ALOADF4(L[1], prow0 + t0 + lane * 8 + 4);                          \
        ALOADF4(L[2], prow0 + t0 + 512 + lane * 8);                        \
        ALOADF4(L[3], prow0 + t0 + 512 + lane * 8 + 4);                    \
        ALOADF4(L[4], prow1 + t0 + lane * 8);                              \
        ALOADF4(L[5], prow1 + t0 + lane * 8 + 4);                          \
        ALOADF4(L[6], prow1 + t0 + 512 + lane * 8);                        \
        ALOADF4(L[7], prow1 + t0 + 512 + lane * 8 + 4);                    \
        if (w == 0) { _Pragma("unroll")                                    \
            for (int j = 0; j < 4; ++j)                                    \
                ALOADI4(T[j], trow + t0 + j * 256 + lane * 4); } } while (0)

    float sl2_0 = 0.f, sp_0 = 0.f, sl2_1 = 0.f, sp_1 = 0.f;

    // convert 8 f32 -> bf16 D,P + f32 sums; write 16B to Dst/Pst row at half h
#define CVT8(u, v, ROW, H, SL, SP, buf) do {                               \
        bf16x8 dd, pp;                                                     \
        const float pvv[8] = {u.x,u.y,u.z,u.w,v.x,v.y,v.z,v.w};            \
        _Pragma("unroll")                                                  \
        for (int j = 0; j < 8; ++j) {                                      \
            const float p = pvv[j];                                        \
            const float pc = fminf(fmaxf(p, EPSF), 1.0f - EPSF);           \
            const float l2p = __log2f(pc), l21p = __log2f(1.0f - pc);      \
            SL += l21p; SP += p;                                           \
            dd[j] = bfc(l21p - l2p); pp[j] = bfc(p);                       \
        }                                                                  \
        *(bf16x8*)&Dst[buf][ROW][(H) * 512 + lane * 8] = dd;               \
        *(bf16x8*)&Pst[buf][ROW][(H) * 512 + lane * 8] = pp; } while (0)

#define WRITE_TILE(buf) do {                                               \
        CVT8(L[0], L[1], k0, 0, sl2_0, sp_0, buf);                         \
        CVT8(L[2], L[3], k0, 1, sl2_0, sp_0, buf);                         \
        CVT8(L[4], L[5], k1, 0, sl2_1, sp_1, buf);                         \
        CVT8(L[6], L[7], k1, 1, sl2_1, sp_1, buf);                         \
        if (w == 0) { _Pragma("unroll")                                    \
            for (int j = 0; j < 4; ++j)                                    \
                *(int4*)&tmt[buf][j * 256 + lane * 4] = T[j]; } } while (0)

    // prologue: tile 0
    ISSUE(0);
    VMDRAIN;
    WRITE_TILE(0);
    __syncthreads();

    f32x4 aD = {0.f,0.f,0.f,0.f}, aP = {0.f,0.f,0.f,0.f};
    float cf = 0.f;
    const int tgt = q + 1;

#pragma unroll 1
    for (int t = 0; t < NT; ++t) {
        const int bi = t & 1;
        if (t + 1 < NT) ISSUE(t + 1);            // in flight under consume
        // consume tile t: wave w owns px [w*128, w*128+128) = 4 k-steps
#pragma unroll
        for (int ks = 0; ks < 4; ++ks) {
            const int px0 = w * 128 + ks * 32 + g * 8;
            const bf16x8 dv = *(const bf16x8*)&Dst[bi][q][px0];
            const bf16x8 pv = *(const bf16x8*)&Pst[bi][q][px0];
            const int4 ta = *(const int4*)&tmt[bi][px0];
            const int4 tb = *(const int4*)&tmt[bi][px0 + 4];
            const int tv[8] = {ta.x,ta.y,ta.z,ta.w,tb.x,tb.y,tb.z,tb.w};
            bf16x8 av;
#pragma unroll
            for (int j = 0; j < 8; ++j) {
                const bool m = (tv[j] == tgt);
                av[j] = m ? (short)0x3F80 : (short)0;
                cf += m ? 1.f : 0.f;
            }
            aD = __builtin_amdgcn_mfma_f32_16x16x32_bf16(av, dv, aD, 0, 0, 0);
            aP = __builtin_amdgcn_mfma_f32_16x16x32_bf16(av, pv, aP, 0, 0, 0);
        }
        if (t + 1 < NT) {
            VMDRAIN;
            WRITE_TILE(bi ^ 1);
        }
        __syncthreads();
    }
#undef ISSUE
#undef WRITE_TILE
#undef CVT8

    // per-channel f32 sums (stager-owned, exact)
    sl2_0 = wave_sum64(sl2_0); sp_0 = wave_sum64(sp_0);
    sl2_1 = wave_sum64(sl2_1); sp_1 = wave_sum64(sp_1);
    if (lane == 0) {
        atomicAdd(&acc[6 + k0], sl2_0);  atomicAdd(&acc[22 + k0], sp_0);
        atomicAdd(&acc[6 + k1], sl2_1);  atomicAdd(&acc[22 + k1], sp_1);
    }
    // cnt: lanes with same q sum over g-groups
    cf += __shfl_xor(cf, 16, 64); cf += __shfl_xor(cf, 32, 64);
    if (lane < 16) sCnt[q][w] = cf;

    // C-frag scatter (m89 layout): n=(lane>>4)*4+r_, k=q
#pragma unroll
    for (int r_ = 0; r_ < 4; ++r_) {
        const int n = ((lane >> 4) << 2) + r_;
        atomicAdd(&gD[n * 16 + q], aD[r_]);
        atomicAdd(&gP[n * 16 + q], aP[r_]);
    }

    // ---- cls (vs tfg) and pred ch0 (vs 1-tfg): 9216 px = 4*2048 + 1024, contiguous ----
    const float* crow = cls + (long)b * HWPX + off;
    const float* zrow = pbase17;
    float s0c=0.f,s1c=0.f,s2c=0.f, s00=0.f,s10=0.f,s20=0.f;
#pragma unroll 1
    for (int c = 0; c < 5; ++c) {
        if (c == 4 && tid >= 256) break;
        const int pb2 = c * 2048 + tid * 4;
        const float4 ca = *(const float4*)(crow + pb2);
        const float4 za = *(const float4*)(zrow + pb2);
        const int4   ua = *(const int4*)(trow + pb2);
        const float cv[4] = {ca.x,ca.y,ca.z,ca.w};
        const float zv[4] = {za.x,za.y,za.z,za.w};
        const int   uv[4] = {ua.x,ua.y,ua.z,ua.w};
#pragma unroll
        for (int j = 0; j < 4; ++j) {
            const int t = uv[j];
            { const float p = cv[j];
              const float pc = fminf(fmaxf(p, EPSF), 1.0f - EPSF);
              const float lp = __log2f(pc), l1p = __log2f(1.0f - pc);
              const bool fg = (t > 0);
              s0c += fg ? lp : l1p; s1c += fg ? p : 0.f; s2c += p; }
            { const float p = zv[j];
              const float pc = fminf(fmaxf(p, EPSF), 1.0f - EPSF);
              const float lp = __log2f(pc), l1p = __log2f(1.0f - pc);
              const bool bg = (t == 0);
              s00 += bg ? lp : l1p; s10 += bg ? p : 0.f; s20 += p; }
        }
    }
    s0c = wave_sum64(s0c); s1c = wave_sum64(s1c); s2c = wave_sum64(s2c);
    s00 = wave_sum64(s00); s10 = wave_sum64(s10); s20 = wave_sum64(s20);
    if (lane == 0) {
        sC6[0][w]=s0c; sC6[1][w]=s1c; sC6[2][w]=s2c;
        sC6[3][w]=s00; sC6[4][w]=s10; sC6[5][w]=s20;
    }
    __syncthreads();

    if (tid < 256) {
        atomicAdd(&acc[38 + tid], gD[tid]);
        atomicAdd(&acc[294 + tid], gP[tid]);
    } else if (tid < 272) {
        const int i = tid - 256;
        float t = 0.f;
#pragma unroll
        for (int ww = 0; ww < 8; ++ww) t += sCnt[i][ww];
        atomicAdd(&acc[550 + i], t);
    } else if (tid < 278) {
        const int i = tid - 272;
        float t = 0.f;
#pragma unroll
        for (int ww = 0; ww < 8; ++ww) t += sC6[i][ww];
        atomicAdd(&acc[i], t);
    }
}

__global__ void loss_final(const float* __restrict__ acc, float* __restrict__ out)
{
    __shared__ float L[16][16];
    __shared__ float s_fg;
    const int tid = threadIdx.x;
    const float Mf = (float)MPIX;

    if (tid == 0) {
        float s = 0.f;
        for (int n = 0; n < 16; ++n) s += acc[550 + n];
        s_fg = s;
    }
    __syncthreads();

    if (tid < 256) {
        const int n = tid >> 4, k = tid & 15;
        const float segD = acc[38 + n * 16 + k];    // log2 units
        const float segP = acc[294 + n * 16 + k];
        const float sump = acc[22 + k];
        const float cn   = acc[550 + n];
        const float bce  = (segD - acc[6 + k]) * LN2F / Mf;
        const float dice = 1.f - (2.f * segP + EPSF) / (sump + cn + EPSF);
        L[n][k] = bce + dice;
    }
    __syncthreads();

    if (tid < 64) {
        const bool mine = (tid < 16);
        float total = 0.f;
        unsigned avail = mine ? 1u : 0u;
        for (int step = 0; step < 16; ++step) {
            float v = (mine && avail) ? L[step][tid] : 1e30f;
            int idx = tid;
            #pragma unroll
            for (int o = 8; o; o >>= 1) {
                const float ov = __shfl_xor(v, o, 64);
                const int   oi = __shfl_xor(idx, o, 64);
                if (ov < v || (ov == v && oi < idx)) { v = ov; idx = oi; }
            }
            if (tid == 0) total += v;
            if (tid == idx) avail = 0;
        }
        if (tid == 0) {
            const float cnt0 = Mf - s_fg;
            const float bce_c  = -acc[0] * LN2F / Mf;
            const float dice_c = 1.f - (2.f * acc[1] + EPSF) / (acc[2] + s_fg + EPSF);
            const float bce_0  = -acc[3] * LN2F / Mf;
            const float dice_0 = 1.f - (2.f * acc[4] + EPSF) / (acc[5] + cnt0 + EPSF);
            const float res = bce_c + dice_c + bce_0 + dice_0;
            out[0] = (res + total) / 16.f;
        }
    }
}

extern "C" void kernel_launch(void* const* d_in, const int* in_sizes, int n_in,
                              void* d_out, int out_size, void* d_ws, size_t ws_size,
                              hipStream_t stream)
{
    const float* pred = (const float*)d_in[0];
    const float* cls  = (const float*)d_in[1];
    const int*   tmi  = (const int*)d_in[2];
    float* acc = (float*)d_ws;

    hipMemsetAsync(d_ws, 0, 566 * sizeof(float), stream);

    loss_main<<<dim3(NBLK), 512, 0, stream>>>(pred, cls, tmi, acc);
    loss_final<<<1, 256, 0, stream>>>(acc, (float*)d_out);
}

// Round 13
// 65.767 us; speedup vs baseline: 1.6689x; 1.6689x over previous
//
#include <hip/hip_runtime.h>
#include <hip/hip_bf16.h>

#define HWPX 589824          // 768*768
#define MPIX 2359296         // 4*768*768
#define EPSF 1e-7f
#define LN2F 0.6931471805599453f
#define PXB  2304            // px per block; 256 blocks/image -> never straddles
#define NBLK 1024            // MPIX / PXB

// ws float layout:
// [0..2]   cls: bce_log2sum, inter, sum_p
// [3..5]   pred ch0 vs (1-tfg): bce_log2sum, inter, sum_p
// [6..21]  a_sum[k]  = sum log2(1-pc), channels k=0..15 (pred ch 1..16)
// [22..37] sum_p[k]
// [38..293]  segD[n*16+k]   (log2 units)
// [294..549] segP[n*16+k]
// [550..565] cntf[n]  float counts of ids 1..16

typedef __attribute__((ext_vector_type(8))) short bf16x8;
typedef __attribute__((ext_vector_type(4))) float f32x4;

__device__ __forceinline__ short bfc(float x) {
    union { __hip_bfloat16 h; short s; } u;
    u.h = __float2bfloat16(x);
    return u.s;
}

__device__ __forceinline__ float wave_sum64(float v) {
#pragma unroll
    for (int o = 32; o; o >>= 1) v += __shfl_xor(v, o, 64);
    return v;
}

// opaque loads into NAMED scalars (no arrays/structs -> guaranteed registers)
#define ALOAD(dst, addr) \
    asm volatile("global_load_dwordx4 %0, %1, off" : "=&v"(dst) : "v"(addr) : "memory")
#define PIPE_WAIT(n) do { \
    asm volatile("s_waitcnt vmcnt(" #n ")" ::: "memory"); \
    __builtin_amdgcn_sched_barrier(0); } while (0)

__global__ __launch_bounds__(512, 4) void loss_main(
    const float* __restrict__ pred, const float* __restrict__ cls,
    const int* __restrict__ tm, float* __restrict__ acc)
{
    __shared__ float sD[8][256];     // per-wave segD C-frags
    __shared__ float sP[8][256];
    __shared__ float sCh[3][16][8];  // {sum_log2_1mp, sum_p, cnt}[ch/bin][wave]
    __shared__ float sC6[6][8];      // cls/ch0 partials

    const int tid  = threadIdx.x;
    const int w    = tid >> 6;       // wave 0..7
    const int lane = tid & 63;
    const int g    = lane >> 4;      // px subgroup 0..3
    const int q    = lane & 15;      // B: channel idx / A: bin idx

    const long base = (long)blockIdx.x * PXB;
    const int b   = (int)(base / HWPX);
    const int off = (int)(base % HWPX);

    const int*   trow = tm   + (long)b * HWPX + off;
    const float* prow = pred + ((long)b * 17 + 1 + q) * (long)HWPX + off;

    f32x4 aD = {0.f, 0.f, 0.f, 0.f};
    f32x4 aP = {0.f, 0.f, 0.f, 0.f};
    float sl2 = 0.f, sp = 0.f, cf = 0.f;
    const int tgt = q + 1;
    const int lbase = w * 32 + g * 8;

    // 12 named registers = 3 pipeline groups, nothing the compiler can demote
    float4 paA, pbA, paB, pbB, paC, pbC;
    int4   taA, tbA, taB, tbB, taC, tbC;

#define ISSUE(S, PA, PB, TA, TB) do { const int _px = lbase + (S) * 256; \
        ALOAD(PA, prow + _px);                                           \
        ALOAD(PB, prow + _px + 4);                                       \
        ALOAD(TA, trow + _px);                                           \
        ALOAD(TB, trow + _px + 4); } while (0)

#define CONSUME(PA, PB, TA, TB) do {                                               \
        const float pv[8] = {PA.x,PA.y,PA.z,PA.w,PB.x,PB.y,PB.z,PB.w};             \
        const int   tv[8] = {TA.x,TA.y,TA.z,TA.w,TB.x,TB.y,TB.z,TB.w};             \
        bf16x8 av, bD, bP;                                                         \
        _Pragma("unroll")                                                          \
        for (int j = 0; j < 8; ++j) {                                              \
            const float p  = pv[j];                                                \
            const float pc = fminf(fmaxf(p, EPSF), 1.0f - EPSF);                   \
            const float l2p  = __log2f(pc);                                        \
            const float l21p = __log2f(1.0f - pc);                                 \
            sl2 += l21p;                                                           \
            sp  += p;                                                              \
            bD[j] = bfc(l21p - l2p);                                               \
            bP[j] = bfc(p);                                                        \
            const bool m = (tv[j] == tgt);                                         \
            av[j] = m ? (short)0x3F80 : (short)0;                                  \
            cf += m ? 1.f : 0.f;                                                   \
        }                                                                          \
        aD = __builtin_amdgcn_mfma_f32_16x16x32_bf16(av, bD, aD, 0, 0, 0);         \
        aP = __builtin_amdgcn_mfma_f32_16x16x32_bf16(av, bP, aP, 0, 0, 0);         \
    } while (0)

    // manually unrolled 9-step, 3-group rotation; 12 loads in flight steady-state
    ISSUE(0, paA, pbA, taA, tbA);
    ISSUE(1, paB, pbB, taB, tbB);
    ISSUE(2, paC, pbC, taC, tbC);  PIPE_WAIT(8);  CONSUME(paA, pbA, taA, tbA);
    ISSUE(3, paA, pbA, taA, tbA);  PIPE_WAIT(8);  CONSUME(paB, pbB, taB, tbB);
    ISSUE(4, paB, pbB, taB, tbB);  PIPE_WAIT(8);  CONSUME(paC, pbC, taC, tbC);
    ISSUE(5, paC, pbC, taC, tbC);  PIPE_WAIT(8);  CONSUME(paA, pbA, taA, tbA);
    ISSUE(6, paA, pbA, taA, tbA);  PIPE_WAIT(8);  CONSUME(paB, pbB, taB, tbB);
    ISSUE(7, paB, pbB, taB, tbB);  PIPE_WAIT(8);  CONSUME(paC, pbC, taC, tbC);
    ISSUE(8, paC, pbC, taC, tbC);  PIPE_WAIT(8);  CONSUME(paA, pbA, taA, tbA);
                                   PIPE_WAIT(4);  CONSUME(paB, pbB, taB, tbB);
                                   PIPE_WAIT(0);  CONSUME(paC, pbC, taC, tbC);
#undef ISSUE
#undef CONSUME

    // reduce per-channel scalars across the 4 px-subgroups (lanes l, l^16, l^32, l^48)
    sl2 += __shfl_xor(sl2, 16, 64); sl2 += __shfl_xor(sl2, 32, 64);
    sp  += __shfl_xor(sp,  16, 64); sp  += __shfl_xor(sp,  32, 64);
    cf  += __shfl_xor(cf,  16, 64); cf  += __shfl_xor(cf,  32, 64);
    if (lane < 16) { sCh[0][q][w] = sl2; sCh[1][q][w] = sp; sCh[2][q][w] = cf; }

    *(f32x4*)&sD[w][lane * 4] = aD;   // element (n,k) at flat ((((n>>2)<<4)|k)<<2)|(n&3)
    *(f32x4*)&sP[w][lane * 4] = aP;

    // ---- cls (vs tfg) and pred ch0 (vs 1-tfg): 2304 px = 512*4 + 64*4 ----
    const float* crow = cls  + (long)b * HWPX + off;
    const float* zrow = pred + (long)b * 17 * (long)HWPX + off;   // channel 0
    float s0c=0.f,s1c=0.f,s2c=0.f, s00=0.f,s10=0.f,s20=0.f;
    const int nch = (tid < 64) ? 2 : 1;
    for (int chunk = 0; chunk < nch; ++chunk) {
        const int pbase = (chunk == 0) ? tid * 4 : 2048 + tid * 4;
        const float4 ca = *(const float4*)(crow + pbase);
        const float4 za = *(const float4*)(zrow + pbase);
        const int4   ua = *(const int4*)(trow + pbase);
        const float cv[4] = {ca.x,ca.y,ca.z,ca.w};
        const float zv[4] = {za.x,za.y,za.z,za.w};
        const int   uv[4] = {ua.x,ua.y,ua.z,ua.w};
#pragma unroll
        for (int j = 0; j < 4; ++j) {
            const int t = uv[j];
            { const float p = cv[j];
              const float pc = fminf(fmaxf(p, EPSF), 1.0f - EPSF);
              const float lp = __log2f(pc), l1p = __log2f(1.0f - pc);
              const bool fg = (t > 0);
              s0c += fg ? lp : l1p; s1c += fg ? p : 0.f; s2c += p; }
            { const float p = zv[j];
              const float pc = fminf(fmaxf(p, EPSF), 1.0f - EPSF);
              const float lp = __log2f(pc), l1p = __log2f(1.0f - pc);
              const bool bg = (t == 0);
              s00 += bg ? lp : l1p; s10 += bg ? p : 0.f; s20 += p; }
        }
    }
    s0c = wave_sum64(s0c); s1c = wave_sum64(s1c); s2c = wave_sum64(s2c);
    s00 = wave_sum64(s00); s10 = wave_sum64(s10); s20 = wave_sum64(s20);
    if (lane == 0) {
        sC6[0][w]=s0c; sC6[1][w]=s1c; sC6[2][w]=s2c;
        sC6[3][w]=s00; sC6[4][w]=s10; sC6[5][w]=s20;
    }
    __syncthreads();

    if (tid < 256) {
        const int n = tid >> 4, k = tid & 15;
        const int idx = ((((n >> 2) << 4) | k) << 2) | (n & 3);
        float dsum = 0.f, psum = 0.f;
#pragma unroll
        for (int ww = 0; ww < 8; ++ww) { dsum += sD[ww][idx]; psum += sP[ww][idx]; }
        atomicAdd(&acc[38 + n * 16 + k], dsum);
        atomicAdd(&acc[294 + n * 16 + k], psum);
    } else if (tid < 304) {
        const int i = tid - 256, qq = i >> 4, ii = i & 15;
        float t = 0.f;
#pragma unroll
        for (int ww = 0; ww < 8; ++ww) t += sCh[qq][ii][ww];
        atomicAdd(&acc[(qq == 0) ? (6 + ii) : (qq == 1) ? (22 + ii) : (550 + ii)], t);
    } else if (tid < 310) {
        const int i = tid - 304;
        float t = 0.f;
#pragma unroll
        for (int ww = 0; ww < 8; ++ww) t += sC6[i][ww];
        atomicAdd(&acc[i], t);
    }
}

__global__ void loss_final(const float* __restrict__ acc, float* __restrict__ out)
{
    __shared__ float L[16][16];
    __shared__ float s_fg;
    const int tid = threadIdx.x;
    const float Mf = (float)MPIX;

    if (tid == 0) {
        float s = 0.f;
        for (int n = 0; n < 16; ++n) s += acc[550 + n];
        s_fg = s;                      // # pixels with id>0 == sum(tfg)
    }
    __syncthreads();

    if (tid < 256) {
        const int n = tid >> 4, k = tid & 15;
        const float segD = acc[38 + n * 16 + k];    // log2 units
        const float segP = acc[294 + n * 16 + k];
        const float sump = acc[22 + k];
        const float cn   = acc[550 + n];
        const float bce  = (segD - acc[6 + k]) * LN2F / Mf;
        const float dice = 1.f - (2.f * segP + EPSF) / (sump + cn + EPSF);
        L[n][k] = bce + dice;
    }
    __syncthreads();

    if (tid < 64) {   // wave 0: greedy assignment on lanes 0..15
        const bool mine = (tid < 16);
        float total = 0.f;
        unsigned avail = mine ? 1u : 0u;
        for (int step = 0; step < 16; ++step) {
            float v = (mine && avail) ? L[step][tid] : 1e30f;
            int idx = tid;
            #pragma unroll
            for (int o = 8; o; o >>= 1) {
                const float ov = __shfl_xor(v, o, 64);
                const int   oi = __shfl_xor(idx, o, 64);
                if (ov < v || (ov == v && oi < idx)) { v = ov; idx = oi; }
            }
            if (tid == 0) total += v;
            if (tid == idx) avail = 0;
        }
        if (tid == 0) {
            const float cnt0 = Mf - s_fg;
            const float bce_c  = -acc[0] * LN2F / Mf;
            const float dice_c = 1.f - (2.f * acc[1] + EPSF) / (acc[2] + s_fg + EPSF);
            const float bce_0  = -acc[3] * LN2F / Mf;
            const float dice_0 = 1.f - (2.f * acc[4] + EPSF) / (acc[5] + cnt0 + EPSF);
            const float res = bce_c + dice_c + bce_0 + dice_0;
            out[0] = (res + total) / 16.f;
        }
    }
}

extern "C" void kernel_launch(void* const* d_in, const int* in_sizes, int n_in,
                              void* d_out, int out_size, void* d_ws, size_t ws_size,
                              hipStream_t stream)
{
    const float* pred = (const float*)d_in[0];
    const float* cls  = (const float*)d_in[1];
    const int*   tmi  = (const int*)d_in[2];
    float* acc = (float*)d_ws;

    hipMemsetAsync(d_ws, 0, 566 * sizeof(float), stream);

    loss_main<<<dim3(NBLK), 512, 0, stream>>>(pred, cls, tmi, acc);
    loss_final<<<1, 256, 0, stream>>>(acc, (float*)d_out);
}